// Round 1
// 189.629 us; speedup vs baseline: 1.0183x; 1.0183x over previous
//
#include <hip/hip_runtime.h>

typedef short  s16x8 __attribute__((ext_vector_type(8)));   // 8 bf16 bit patterns
typedef float  f32x4 __attribute__((ext_vector_type(4)));
typedef float  f32x2 __attribute__((ext_vector_type(2)));
typedef unsigned int u32;
typedef unsigned int u32x4 __attribute__((ext_vector_type(4)));
typedef unsigned short u16;

#define DEVI static __device__ __forceinline__

#if __has_builtin(__builtin_amdgcn_exp2f)
#define EXP2(v) __builtin_amdgcn_exp2f(v)   // raw v_exp_f32 (R11-proven)
#else
#define EXP2(v) exp2f(v)
#endif

constexpr int T_  = 128;
constexpr int F_  = 14;
constexpr int H_  = 64;
constexpr int BPB = 16;   // batch rows per block
constexpr int K_  = 8;    // timesteps per epoch (chunk)
constexpr int NCH = T_ / K_;   // 16 chunks

DEVI u16 f2bf(float f) {                     // RNE, one-time weight convert
  u32 u = __builtin_bit_cast(u32, f);
  u += 0x7fffu + ((u >> 16) & 1u);
  return (u16)(u >> 16);
}
DEVI u16 f2bfF(float f) {                    // round-half-up (x / h in-loop path)
  u32 u = __builtin_bit_cast(u32, f);
  return (u16)((u + 0x8000u) >> 16);
}
DEVI u32 pkbf(float a, float b) {            // pack 2 bf16 into one dword
  u32 ua = __builtin_bit_cast(u32, a) + 0x8000u;
  u32 ub = __builtin_bit_cast(u32, b) + 0x8000u;
  return (ua >> 16) | (ub & 0xffff0000u);
}
// B-frag kt from tanh'd acc tiles: elements 0-3 = tile kt, 4-7 = tile kt+2
DEVI s16x8 packfrag(const f32x4& a, const f32x4& b) {
  u32x4 p;
  p[0] = pkbf(a[0], a[1]); p[1] = pkbf(a[2], a[3]);
  p[2] = pkbf(b[0], b[1]); p[3] = pkbf(b[2], b[3]);
  return __builtin_bit_cast(s16x8, p);
}
DEVI float tanhfast(float x) {               // 5 instrs with raw exp2
  float e = EXP2(x * -2.8853900817779268f);
  float r = __builtin_amdgcn_rcpf(1.0f + e);
  return __builtin_fmaf(2.0f, r, -1.0f);
}
DEVI f32x4 tanh4(const f32x4& v) {
  f32x4 r;
  r[0] = tanhfast(v[0]); r[1] = tanhfast(v[1]);
  r[2] = tanhfast(v[2]); r[3] = tanhfast(v[3]);
  return r;
}
DEVI f32x4 MFMA(s16x8 a, s16x8 b, f32x4 c) {
  return __builtin_amdgcn_mfma_f32_16x16x32_bf16(a, b, c, 0, 0, 0);
}
DEVI s16x8 ldrow8(const float* p) {          // 8 contiguous fp32 -> bf16 A-frag
  const f32x4 a = ((const f32x4*)p)[0];
  const f32x4 b = ((const f32x4*)p)[1];
  s16x8 r;
  r[0] = (short)f2bf(a[0]); r[1] = (short)f2bf(a[1]);
  r[2] = (short)f2bf(a[2]); r[3] = (short)f2bf(a[3]);
  r[4] = (short)f2bf(b[0]); r[5] = (short)f2bf(b[1]);
  r[6] = (short)f2bf(b[2]); r[7] = (short)f2bf(b[3]);
  return r;
}

// 3 waves/block; wave w owns layer w FULLY (R8-proven math/layout/dbuf protocol).
// Chunked pipeline (K_=8) as before.  THIS ROUND (schedule-only, arithmetic
// bit-identical => absmax must stay 5.859375e-3):
//  * waves 1/2 prefetch the WHOLE chunk's Fp frags (16x ds_read_b128) into
//    registers at chunk top -> per-step LDS latency off the recurrence chain
//  * q (input projection, independent of the recurrence) is software-pipelined
//    one step ahead: q[k+1] issues while step k's tanh/pack runs
//  * tanh/pack split: F[0] (tiles 0,2) produced before tiles 1,3 so the next
//    step's first MFMA pair can start earlier
//  * wave0 spreads next-chunk x conversion across steps (elem k-2 at step k)
//    instead of a serial epoch tail; raw-x staging registers are overlaid with
//    the Fp prefetch registers (never live in the same wave)
__global__ __launch_bounds__(192, 1) void rnn_ck(
    const float* __restrict__ x,
    const float* __restrict__ Wih0, const float* __restrict__ Whh0,
    const float* __restrict__ bih0, const float* __restrict__ bhh0,
    const float* __restrict__ Wih1, const float* __restrict__ Whh1,
    const float* __restrict__ bih1, const float* __restrict__ bhh1,
    const float* __restrict__ Wih2, const float* __restrict__ Whh2,
    const float* __restrict__ bih2, const float* __restrict__ bhh2,
    const float* __restrict__ fc1w, const float* __restrict__ fc1b,
    const float* __restrict__ fc2w, const float* __restrict__ fc2b,
    float* __restrict__ out)
{
  // [par][layer01][k][frag][lane] = 65536 B (R10 proved 64KiB static works).
  __shared__ __align__(16) u32x4 hf[2][2][K_][2][64];

  const int tid  = threadIdx.x;
  const int w    = tid >> 6;        // wave id = layer id
  const int lane = tid & 63;
  const int g    = lane >> 4;
  const int m    = lane & 15;
  const int b0   = blockIdx.x * BPB;

  f32x4 z4; z4[0] = 0.f; z4[1] = 0.f; z4[2] = 0.f; z4[3] = 0.f;

  // ---- per-wave (per-layer) weights, all register-resident (R8-verbatim) ----
  s16x8 Ax[4], Ai[4][2], Ah[4][2];
  f32x4 bc[4];
  {
    const float* Wi = Wih1; const float* Wh = Whh0;
    const float* bi = bih0; const float* bh = bhh0;
    if (w == 1)      { Wi = Wih1; Wh = Whh1; bi = bih1; bh = bhh1; }
    else if (w == 2) { Wi = Wih2; Wh = Whh2; bi = bih2; bh = bhh2; }
    #pragma unroll
    for (int n = 0; n < 4; n++) {
      const int Lr = 32 * (n & 1) + 8 * (m >> 2) + 4 * (n >> 1) + (m & 3);
      if (w == 0) {                      // input side 64x14, zero-pad K to 32
        s16x8 r;
        #pragma unroll
        for (int j2 = 0; j2 < 8; j2++) {
          const int kk = 8 * g + j2;
          r[j2] = (kk < F_) ? (short)f2bf(Wih0[Lr * F_ + kk]) : (short)0;
        }
        Ax[n] = r;
        Ai[n][0] = r; Ai[n][1] = r;      // dead in wave0
      } else {
        #pragma unroll
        for (int kt = 0; kt < 2; kt++)
          Ai[n][kt] = ldrow8(Wi + Lr * H_ + 32 * kt + 8 * g);
        Ax[n] = Ai[n][0];                // dead in waves 1/2
      }
      #pragma unroll
      for (int kt = 0; kt < 2; kt++)
        Ah[n][kt] = ldrow8(Wh + Lr * H_ + 32 * kt + 8 * g);
      const int Lb = 32 * (n & 1) + 8 * g + 4 * (n >> 1);
      bc[n] = *(const f32x4*)(bi + Lb) + *(const f32x4*)(bh + Lb);
    }
  }

  // ---- hh-state frags (own layer), zero init (h(-1)=0 in REGISTERS) ----
  s16x8 F[2];
  {
    s16x8 z;
    #pragma unroll
    for (int i = 0; i < 8; i++) z[i] = 0;
    F[0] = z; F[1] = z;
  }
  f32x4 h2v[4];
  #pragma unroll
  for (int n = 0; n < 4; n++) h2v[n] = z4;

  // ---- wave-0 x pipeline: chunk-granular register prefetch ----
  const float* xrow = x + (size_t)(b0 + m) * T_ * F_;
  auto ldraw = [&](int t, f32x4& ra, f32x4& rb) {    // R8-proven float2 loads
    const float* p = xrow + t * F_;
    if (g == 0) {
      f32x2 p0 = *(const f32x2*)(p),     p1 = *(const f32x2*)(p + 2);
      f32x2 p2 = *(const f32x2*)(p + 4), p3 = *(const f32x2*)(p + 6);
      ra[0] = p0[0]; ra[1] = p0[1]; ra[2] = p1[0]; ra[3] = p1[1];
      rb[0] = p2[0]; rb[1] = p2[1]; rb[2] = p3[0]; rb[3] = p3[1];
    } else if (g == 1) {
      f32x2 p4 = *(const f32x2*)(p + 8), p5 = *(const f32x2*)(p + 10);
      f32x2 p6 = *(const f32x2*)(p + 12);
      ra[0] = p4[0]; ra[1] = p4[1]; ra[2] = p5[0]; ra[3] = p5[1];
      rb[0] = p6[0]; rb[1] = p6[1]; rb[2] = 0.f;   rb[3] = 0.f;
    } else {
      ra = z4; rb = z4;
    }
  };
  auto cvtraw = [&](const f32x4& ra, const f32x4& rb) -> s16x8 {
    s16x8 r;
    r[0] = (short)f2bfF(ra[0]); r[1] = (short)f2bfF(ra[1]);
    r[2] = (short)f2bfF(ra[2]); r[3] = (short)f2bfF(ra[3]);
    r[4] = (short)f2bfF(rb[0]); r[5] = (short)f2bfF(rb[1]);
    r[6] = (short)f2bfF(rb[2]); r[7] = (short)f2bfF(rb[3]);
    return r;
  };

  s16x8 cur[K_];              // current chunk's x frags (wave0)
  {
    // initial chunk: load + convert (prologue only; in-loop staging uses
    // the overlaid stage[] array below)
    f32x4 ira[K_], irb[K_];
    if (w == 0) {
      #pragma unroll
      for (int k = 0; k < K_; k++) { ldraw(k, ira[k], irb[k]); }
      #pragma unroll
      for (int k = 0; k < K_; k++) cur[k] = cvtraw(ira[k], irb[k]);
    }
  }

  // ---- chunked pipelined loop: epoch e, wave w does chunk c = e - w ----
  #pragma unroll 1
  for (int e = 0; e < NCH + 2; e++) {
    const int c    = e - w;
    const int wb   = e & 1, rbuf = (e & 1) ^ 1;

    // stage[]: wave0 = next chunk raw x (stage[k]=ra, stage[8+k]=rb);
    // waves1/2 = prefetched Fp frags (stage[k]=P0[k], stage[8+k]=P1[k]).
    // Never live in the same wave -> one register footprint.
    f32x4 stage[2 * K_];

    if (w == 0) {                        // issue next chunk's loads NOW
      int cn = e + 1; if (cn > NCH - 1) cn = NCH - 1;
      #pragma unroll
      for (int k = 0; k < K_; k++) ldraw(cn * K_ + k, stage[k], stage[K_ + k]);
    }

    if (c >= 0 && c < NCH) {             // wave-uniform
      // ---- chunk-top LDS prefetch (waves 1/2): whole chunk's Fp -> regs ----
      if (w > 0) {
        const int src = w - 1;
        #pragma unroll
        for (int k = 0; k < K_; k++) {
          stage[k]      = __builtin_bit_cast(f32x4, hf[rbuf][src][k][0][lane]);
          stage[K_ + k] = __builtin_bit_cast(f32x4, hf[rbuf][src][k][1][lane]);
        }
      }

      // ---- q prologue (step 0's input projection; values identical) ----
      f32x4 qc[4], qn[4];
      if (w == 0) {
        #pragma unroll
        for (int n = 0; n < 4; n++) qc[n] = MFMA(Ax[n], cur[0], z4);
      } else {
        const s16x8 P0 = __builtin_bit_cast(s16x8, stage[0]);
        const s16x8 P1 = __builtin_bit_cast(s16x8, stage[K_]);
        #pragma unroll
        for (int n = 0; n < 4; n++) qc[n] = MFMA(Ai[n][0], P0, z4);
        #pragma unroll
        for (int n = 0; n < 4; n++) qc[n] = MFMA(Ai[n][1], P1, qc[n]);
      }

      #pragma unroll
      for (int k = 0; k < K_; k++) {
        // next step's q — independent of the recurrence, issue early
        if (k + 1 < K_) {
          if (w == 0) {
            #pragma unroll
            for (int n = 0; n < 4; n++) qn[n] = MFMA(Ax[n], cur[k + 1], z4);
          } else {
            const s16x8 P0 = __builtin_bit_cast(s16x8, stage[k + 1]);
            const s16x8 P1 = __builtin_bit_cast(s16x8, stage[K_ + k + 1]);
            #pragma unroll
            for (int n = 0; n < 4; n++) qn[n] = MFMA(Ai[n][0], P0, z4);
            #pragma unroll
            for (int n = 0; n < 4; n++) qn[n] = MFMA(Ai[n][1], P1, qn[n]);
          }
        }

        // recurrence chain: p = bc + Whh*h  (2 dependent MFMAs)
        f32x4 p[4];
        #pragma unroll
        for (int n = 0; n < 4; n++) p[n] = MFMA(Ah[n][0], F[0], bc[n]);
        #pragma unroll
        for (int n = 0; n < 4; n++) p[n] = MFMA(Ah[n][1], F[1], p[n]);

        // F[0] first (tiles 0,2) so next step's first MFMA pair starts early
        f32x4 hv0 = tanh4(p[0] + qc[0]);
        f32x4 hv2 = tanh4(p[2] + qc[2]);
        F[0] = packfrag(hv0, hv2);
        f32x4 hv1 = tanh4(p[1] + qc[1]);
        f32x4 hv3 = tanh4(p[3] + qc[3]);
        F[1] = packfrag(hv1, hv3);

        if (w < 2) {
          hf[wb][w][k][0][lane] = __builtin_bit_cast(u32x4, F[0]);
          hf[wb][w][k][1][lane] = __builtin_bit_cast(u32x4, F[1]);
        } else if (c == NCH - 1 && k == K_ - 1) {
          h2v[0] = hv0; h2v[1] = hv1;    // fp32 h2 for head
          h2v[2] = hv2; h2v[3] = hv3;
        }

        if (k + 1 < K_) {
          #pragma unroll
          for (int n = 0; n < 4; n++) qc[n] = qn[n];
        }

        // wave0: spread next-chunk cvt — elem k-2 at step k (~2 steps of
        // load-latency cover; cur[k-2] is dead, last read at step k-3)
        if (w == 0 && k >= 2)
          cur[k - 2] = cvtraw(stage[k - 2], stage[K_ + k - 2]);
      }

      if (w == 0) {                      // tail: last two elements
        cur[K_ - 2] = cvtraw(stage[K_ - 2], stage[2 * K_ - 2]);
        cur[K_ - 1] = cvtraw(stage[K_ - 1], stage[2 * K_ - 1]);
      }
    }
    __syncthreads();   // single chunk-granular barrier (R8 dbuf protocol)
  }

  // ---- FC head: h2l overlays dead hf; wave 2 un-permutes, wave 0 computes ----
  float (*h2l)[68] = (float (*)[68])&hf[0][0][0][0][0];
  if (w == 2) {
    #pragma unroll
    for (int n = 0; n < 4; n++) {
      const int Lb = 32 * (n & 1) + 8 * g + 4 * (n >> 1);
      *(f32x4*)&h2l[m][Lb] = h2v[n];
    }
  }
  __syncthreads();

  if (w == 0) {
    float hr[64];
    #pragma unroll
    for (int q = 0; q < 16; q++) {
      f32x4 v = *(const f32x4*)&h2l[m][4 * q];
      hr[4 * q + 0] = v[0]; hr[4 * q + 1] = v[1];
      hr[4 * q + 2] = v[2]; hr[4 * q + 3] = v[3];
    }
    float acc2 = 0.f;
    #pragma unroll
    for (int jj = 0; jj < 8; jj++) {
      const int jf = 8 * g + jj;
      float s = fc1b[jf];
      const f32x4* wp = (const f32x4*)(fc1w + jf * H_);
      #pragma unroll
      for (int kq = 0; kq < 16; kq++) {
        f32x4 wv = wp[kq];
        s += hr[4 * kq + 0] * wv[0] + hr[4 * kq + 1] * wv[1]
           + hr[4 * kq + 2] * wv[2] + hr[4 * kq + 3] * wv[3];
      }
      s = fmaxf(s, 0.f);
      acc2 += s * fc2w[jf];
    }
    acc2 += __shfl_xor(acc2, 16, 64);
    acc2 += __shfl_xor(acc2, 32, 64);
    if (lane < 16) out[b0 + m] = acc2 + fc2b[0];
  }
}

extern "C" void kernel_launch(void* const* d_in, const int* in_sizes, int n_in,
                              void* d_out, int out_size, void* d_ws, size_t ws_size,
                              hipStream_t stream) {
  const float* x    = (const float*)d_in[0];
  const float* Wih0 = (const float*)d_in[1];
  const float* Whh0 = (const float*)d_in[2];
  const float* bih0 = (const float*)d_in[3];
  const float* bhh0 = (const float*)d_in[4];
  const float* Wih1 = (const float*)d_in[5];
  const float* Whh1 = (const float*)d_in[6];
  const float* bih1 = (const float*)d_in[7];
  const float* bhh1 = (const float*)d_in[8];
  const float* Wih2 = (const float*)d_in[9];
  const float* Whh2 = (const float*)d_in[10];
  const float* bih2 = (const float*)d_in[11];
  const float* bhh2 = (const float*)d_in[12];
  const float* fc1w = (const float*)d_in[13];
  const float* fc1b = (const float*)d_in[14];
  const float* fc2w = (const float*)d_in[15];
  const float* fc2b = (const float*)d_in[16];

  rnn_ck<<<dim3(4096 / BPB), dim3(192), 0, stream>>>(
      x, Wih0, Whh0, bih0, bhh0, Wih1, Whh1, bih1, bhh1,
      Wih2, Whh2, bih2, bhh2, fc1w, fc1b, fc2w, fc2b, (float*)d_out);
}

// Round 2
// 179.685 us; speedup vs baseline: 1.0746x; 1.0553x over previous
//
#include <hip/hip_runtime.h>

typedef short  s16x8 __attribute__((ext_vector_type(8)));   // 8 bf16 bit patterns
typedef float  f32x4 __attribute__((ext_vector_type(4)));
typedef float  f32x2 __attribute__((ext_vector_type(2)));
typedef unsigned int u32;
typedef unsigned int u32x4 __attribute__((ext_vector_type(4)));
typedef unsigned short u16;

#define DEVI static __device__ __forceinline__

#if __has_builtin(__builtin_amdgcn_exp2f)
#define EXP2(v) __builtin_amdgcn_exp2f(v)   // raw v_exp_f32 (R11-proven)
#else
#define EXP2(v) exp2f(v)
#endif

constexpr int T_  = 128;
constexpr int F_  = 14;
constexpr int H_  = 64;
constexpr int BPB = 16;   // batch rows per block
constexpr int K_  = 8;    // timesteps per epoch (chunk)
constexpr int NCH = T_ / K_;   // 16 chunks

DEVI u16 f2bf(float f) {                     // RNE, one-time weight convert
  u32 u = __builtin_bit_cast(u32, f);
  u += 0x7fffu + ((u >> 16) & 1u);
  return (u16)(u >> 16);
}
// HW packed bf16 convert (RNE): 1 instr replaces 5-op manual pack.
// Differs from old round-half-up ONLY on exact ties (lo16==0x8000) -> results
// statistically identical; proven inline-asm->MFMA pattern (learn_hip m214v22).
DEVI u32 cvtpk(float a, float b) {           // lo16 = bf16(a), hi16 = bf16(b)
  u32 r;
  asm("v_cvt_pk_bf16_f32 %0, %1, %2" : "=v"(r) : "v"(a), "v"(b));
  return r;
}
// B-frag kt from tanh'd acc tiles: elements 0-3 = tile kt, 4-7 = tile kt+2
DEVI s16x8 packfrag(const f32x4& a, const f32x4& b) {
  u32x4 p;
  p[0] = cvtpk(a[0], a[1]); p[1] = cvtpk(a[2], a[3]);
  p[2] = cvtpk(b[0], b[1]); p[3] = cvtpk(b[2], b[3]);
  return __builtin_bit_cast(s16x8, p);
}
// tanh over 4 lanes; mul/add/fma vectorized -> v_pk_*_f32 (gfx90a+ packed fp32,
// bit-identical to scalar); exp2/rcp remain scalar transcendentals.
DEVI f32x4 tanh4(const f32x4& v) {
  const f32x4 kC = -2.8853900817779268f;
  f32x4 t = v * kC;                          // 2x v_pk_mul_f32
  f32x4 e;
  e[0] = EXP2(t[0]); e[1] = EXP2(t[1]);
  e[2] = EXP2(t[2]); e[3] = EXP2(t[3]);
  const f32x4 kOne = 1.0f;
  f32x4 d = e + kOne;                        // 2x v_pk_add_f32
  f32x4 r;
  r[0] = __builtin_amdgcn_rcpf(d[0]); r[1] = __builtin_amdgcn_rcpf(d[1]);
  r[2] = __builtin_amdgcn_rcpf(d[2]); r[3] = __builtin_amdgcn_rcpf(d[3]);
  const f32x4 kTwo = 2.0f, kNegOne = -1.0f;
  return __builtin_elementwise_fma(kTwo, r, kNegOne);   // 2x v_pk_fma_f32
}
DEVI f32x4 MFMA(s16x8 a, s16x8 b, f32x4 c) {
  return __builtin_amdgcn_mfma_f32_16x16x32_bf16(a, b, c, 0, 0, 0);
}
DEVI s16x8 ldrow8(const float* p) {          // 8 contiguous fp32 -> bf16 A-frag
  const f32x4 a = ((const f32x4*)p)[0];
  const f32x4 b = ((const f32x4*)p)[1];
  s16x8 r;
  r[0] = (short)f2bf(a[0]); r[1] = (short)f2bf(a[1]);
  r[2] = (short)f2bf(a[2]); r[3] = (short)f2bf(a[3]);
  r[4] = (short)f2bf(b[0]); r[5] = (short)f2bf(b[1]);
  r[6] = (short)f2bf(b[2]); r[7] = (short)f2bf(b[3]);
  return r;
}

// 3 waves/block; wave w owns layer w FULLY (R8-proven math/layout/dbuf protocol).
// Chunked pipeline (K_=8), chunk-top LDS prefetch + 1-deep q pipeline (R1).
// THIS ROUND: issue-count reduction — counters showed ~57% of each step is
// instruction issue on the 3 active SIMDs, dominated by manual bf16 packing
// (40 VALU ops/step), wave0 x-convert (~50 ops/step) and tanh scalar math.
//  * packfrag / cvtraw via v_cvt_pk_bf16_f32 (RNE; tie-only value change)
//  * tanh + p+q adds vectorized to packed fp32 (bit-identical)
__global__ __launch_bounds__(192, 1) void rnn_ck(
    const float* __restrict__ x,
    const float* __restrict__ Wih0, const float* __restrict__ Whh0,
    const float* __restrict__ bih0, const float* __restrict__ bhh0,
    const float* __restrict__ Wih1, const float* __restrict__ Whh1,
    const float* __restrict__ bih1, const float* __restrict__ bhh1,
    const float* __restrict__ Wih2, const float* __restrict__ Whh2,
    const float* __restrict__ bih2, const float* __restrict__ bhh2,
    const float* __restrict__ fc1w, const float* __restrict__ fc1b,
    const float* __restrict__ fc2w, const float* __restrict__ fc2b,
    float* __restrict__ out)
{
  // [par][layer01][k][frag][lane] = 65536 B (R10 proved 64KiB static works).
  __shared__ __align__(16) u32x4 hf[2][2][K_][2][64];

  const int tid  = threadIdx.x;
  const int w    = tid >> 6;        // wave id = layer id
  const int lane = tid & 63;
  const int g    = lane >> 4;
  const int m    = lane & 15;
  const int b0   = blockIdx.x * BPB;

  f32x4 z4; z4[0] = 0.f; z4[1] = 0.f; z4[2] = 0.f; z4[3] = 0.f;

  // ---- per-wave (per-layer) weights, all register-resident (R8-verbatim) ----
  s16x8 Ax[4], Ai[4][2], Ah[4][2];
  f32x4 bc[4];
  {
    const float* Wi = Wih1; const float* Wh = Whh0;
    const float* bi = bih0; const float* bh = bhh0;
    if (w == 1)      { Wi = Wih1; Wh = Whh1; bi = bih1; bh = bhh1; }
    else if (w == 2) { Wi = Wih2; Wh = Whh2; bi = bih2; bh = bhh2; }
    #pragma unroll
    for (int n = 0; n < 4; n++) {
      const int Lr = 32 * (n & 1) + 8 * (m >> 2) + 4 * (n >> 1) + (m & 3);
      if (w == 0) {                      // input side 64x14, zero-pad K to 32
        s16x8 r;
        #pragma unroll
        for (int j2 = 0; j2 < 8; j2++) {
          const int kk = 8 * g + j2;
          r[j2] = (kk < F_) ? (short)f2bf(Wih0[Lr * F_ + kk]) : (short)0;
        }
        Ax[n] = r;
        Ai[n][0] = r; Ai[n][1] = r;      // dead in wave0
      } else {
        #pragma unroll
        for (int kt = 0; kt < 2; kt++)
          Ai[n][kt] = ldrow8(Wi + Lr * H_ + 32 * kt + 8 * g);
        Ax[n] = Ai[n][0];                // dead in waves 1/2
      }
      #pragma unroll
      for (int kt = 0; kt < 2; kt++)
        Ah[n][kt] = ldrow8(Wh + Lr * H_ + 32 * kt + 8 * g);
      const int Lb = 32 * (n & 1) + 8 * g + 4 * (n >> 1);
      bc[n] = *(const f32x4*)(bi + Lb) + *(const f32x4*)(bh + Lb);
    }
  }

  // ---- hh-state frags (own layer), zero init (h(-1)=0 in REGISTERS) ----
  s16x8 F[2];
  {
    s16x8 z;
    #pragma unroll
    for (int i = 0; i < 8; i++) z[i] = 0;
    F[0] = z; F[1] = z;
  }
  f32x4 h2v[4];
  #pragma unroll
  for (int n = 0; n < 4; n++) h2v[n] = z4;

  // ---- wave-0 x pipeline: chunk-granular register prefetch ----
  const float* xrow = x + (size_t)(b0 + m) * T_ * F_;
  auto ldraw = [&](int t, f32x4& ra, f32x4& rb) {    // R8-proven float2 loads
    const float* p = xrow + t * F_;
    if (g == 0) {
      f32x2 p0 = *(const f32x2*)(p),     p1 = *(const f32x2*)(p + 2);
      f32x2 p2 = *(const f32x2*)(p + 4), p3 = *(const f32x2*)(p + 6);
      ra[0] = p0[0]; ra[1] = p0[1]; ra[2] = p1[0]; ra[3] = p1[1];
      rb[0] = p2[0]; rb[1] = p2[1]; rb[2] = p3[0]; rb[3] = p3[1];
    } else if (g == 1) {
      f32x2 p4 = *(const f32x2*)(p + 8), p5 = *(const f32x2*)(p + 10);
      f32x2 p6 = *(const f32x2*)(p + 12);
      ra[0] = p4[0]; ra[1] = p4[1]; ra[2] = p5[0]; ra[3] = p5[1];
      rb[0] = p6[0]; rb[1] = p6[1]; rb[2] = 0.f;   rb[3] = 0.f;
    } else {
      ra = z4; rb = z4;
    }
  };
  auto cvtraw = [&](const f32x4& ra, const f32x4& rb) -> s16x8 {
    u32x4 p;
    p[0] = cvtpk(ra[0], ra[1]); p[1] = cvtpk(ra[2], ra[3]);
    p[2] = cvtpk(rb[0], rb[1]); p[3] = cvtpk(rb[2], rb[3]);
    return __builtin_bit_cast(s16x8, p);
  };

  s16x8 cur[K_];              // current chunk's x frags (wave0)
  {
    // initial chunk: load + convert (prologue only; in-loop staging uses
    // the overlaid stage[] array below)
    f32x4 ira[K_], irb[K_];
    if (w == 0) {
      #pragma unroll
      for (int k = 0; k < K_; k++) { ldraw(k, ira[k], irb[k]); }
      #pragma unroll
      for (int k = 0; k < K_; k++) cur[k] = cvtraw(ira[k], irb[k]);
    }
  }

  // ---- chunked pipelined loop: epoch e, wave w does chunk c = e - w ----
  #pragma unroll 1
  for (int e = 0; e < NCH + 2; e++) {
    const int c    = e - w;
    const int wb   = e & 1, rbuf = (e & 1) ^ 1;

    // stage[]: wave0 = next chunk raw x (stage[k]=ra, stage[8+k]=rb);
    // waves1/2 = prefetched Fp frags (stage[k]=P0[k], stage[8+k]=P1[k]).
    // Never live in the same wave -> one register footprint.
    f32x4 stage[2 * K_];

    if (w == 0) {                        // issue next chunk's loads NOW
      int cn = e + 1; if (cn > NCH - 1) cn = NCH - 1;
      #pragma unroll
      for (int k = 0; k < K_; k++) ldraw(cn * K_ + k, stage[k], stage[K_ + k]);
    }

    if (c >= 0 && c < NCH) {             // wave-uniform
      // ---- chunk-top LDS prefetch (waves 1/2): whole chunk's Fp -> regs ----
      if (w > 0) {
        const int src = w - 1;
        #pragma unroll
        for (int k = 0; k < K_; k++) {
          stage[k]      = __builtin_bit_cast(f32x4, hf[rbuf][src][k][0][lane]);
          stage[K_ + k] = __builtin_bit_cast(f32x4, hf[rbuf][src][k][1][lane]);
        }
      }

      // ---- q prologue (step 0's input projection; values identical) ----
      f32x4 qc[4], qn[4];
      if (w == 0) {
        #pragma unroll
        for (int n = 0; n < 4; n++) qc[n] = MFMA(Ax[n], cur[0], z4);
      } else {
        const s16x8 P0 = __builtin_bit_cast(s16x8, stage[0]);
        const s16x8 P1 = __builtin_bit_cast(s16x8, stage[K_]);
        #pragma unroll
        for (int n = 0; n < 4; n++) qc[n] = MFMA(Ai[n][0], P0, z4);
        #pragma unroll
        for (int n = 0; n < 4; n++) qc[n] = MFMA(Ai[n][1], P1, qc[n]);
      }

      #pragma unroll
      for (int k = 0; k < K_; k++) {
        // next step's q — independent of the recurrence, issue early
        if (k + 1 < K_) {
          if (w == 0) {
            #pragma unroll
            for (int n = 0; n < 4; n++) qn[n] = MFMA(Ax[n], cur[k + 1], z4);
          } else {
            const s16x8 P0 = __builtin_bit_cast(s16x8, stage[k + 1]);
            const s16x8 P1 = __builtin_bit_cast(s16x8, stage[K_ + k + 1]);
            #pragma unroll
            for (int n = 0; n < 4; n++) qn[n] = MFMA(Ai[n][0], P0, z4);
            #pragma unroll
            for (int n = 0; n < 4; n++) qn[n] = MFMA(Ai[n][1], P1, qn[n]);
          }
        }

        // recurrence chain: p = bc + Whh*h  (2 dependent MFMAs).
        // Tiles 0,2 first so F[0]'s inputs retire first.
        f32x4 p[4];
        p[0] = MFMA(Ah[0][0], F[0], bc[0]);
        p[2] = MFMA(Ah[2][0], F[0], bc[2]);
        p[1] = MFMA(Ah[1][0], F[0], bc[1]);
        p[3] = MFMA(Ah[3][0], F[0], bc[3]);
        p[0] = MFMA(Ah[0][1], F[1], p[0]);
        p[2] = MFMA(Ah[2][1], F[1], p[2]);
        p[1] = MFMA(Ah[1][1], F[1], p[1]);
        p[3] = MFMA(Ah[3][1], F[1], p[3]);

        // F[0] first (tiles 0,2) so next step's first MFMA pair starts early
        f32x4 hv0 = tanh4(p[0] + qc[0]);
        f32x4 hv2 = tanh4(p[2] + qc[2]);
        F[0] = packfrag(hv0, hv2);
        f32x4 hv1 = tanh4(p[1] + qc[1]);
        f32x4 hv3 = tanh4(p[3] + qc[3]);
        F[1] = packfrag(hv1, hv3);

        if (w < 2) {
          hf[wb][w][k][0][lane] = __builtin_bit_cast(u32x4, F[0]);
          hf[wb][w][k][1][lane] = __builtin_bit_cast(u32x4, F[1]);
        } else if (c == NCH - 1 && k == K_ - 1) {
          h2v[0] = hv0; h2v[1] = hv1;    // fp32 h2 for head
          h2v[2] = hv2; h2v[3] = hv3;
        }

        if (k + 1 < K_) {
          #pragma unroll
          for (int n = 0; n < 4; n++) qc[n] = qn[n];
        }

        // wave0: spread next-chunk cvt — elem k-2 at step k (~2 steps of
        // load-latency cover; cur[k-2] is dead, last read at step k-3)
        if (w == 0 && k >= 2)
          cur[k - 2] = cvtraw(stage[k - 2], stage[K_ + k - 2]);
      }

      if (w == 0) {                      // tail: last two elements
        cur[K_ - 2] = cvtraw(stage[K_ - 2], stage[2 * K_ - 2]);
        cur[K_ - 1] = cvtraw(stage[K_ - 1], stage[2 * K_ - 1]);
      }
    }
    __syncthreads();   // single chunk-granular barrier (R8 dbuf protocol)
  }

  // ---- FC head: h2l overlays dead hf; wave 2 un-permutes, wave 0 computes ----
  float (*h2l)[68] = (float (*)[68])&hf[0][0][0][0][0];
  if (w == 2) {
    #pragma unroll
    for (int n = 0; n < 4; n++) {
      const int Lb = 32 * (n & 1) + 8 * g + 4 * (n >> 1);
      *(f32x4*)&h2l[m][Lb] = h2v[n];
    }
  }
  __syncthreads();

  if (w == 0) {
    float hr[64];
    #pragma unroll
    for (int q = 0; q < 16; q++) {
      f32x4 v = *(const f32x4*)&h2l[m][4 * q];
      hr[4 * q + 0] = v[0]; hr[4 * q + 1] = v[1];
      hr[4 * q + 2] = v[2]; hr[4 * q + 3] = v[3];
    }
    float acc2 = 0.f;
    #pragma unroll
    for (int jj = 0; jj < 8; jj++) {
      const int jf = 8 * g + jj;
      float s = fc1b[jf];
      const f32x4* wp = (const f32x4*)(fc1w + jf * H_);
      #pragma unroll
      for (int kq = 0; kq < 16; kq++) {
        f32x4 wv = wp[kq];
        s += hr[4 * kq + 0] * wv[0] + hr[4 * kq + 1] * wv[1]
           + hr[4 * kq + 2] * wv[2] + hr[4 * kq + 3] * wv[3];
      }
      s = fmaxf(s, 0.f);
      acc2 += s * fc2w[jf];
    }
    acc2 += __shfl_xor(acc2, 16, 64);
    acc2 += __shfl_xor(acc2, 32, 64);
    if (lane < 16) out[b0 + m] = acc2 + fc2b[0];
  }
}

extern "C" void kernel_launch(void* const* d_in, const int* in_sizes, int n_in,
                              void* d_out, int out_size, void* d_ws, size_t ws_size,
                              hipStream_t stream) {
  const float* x    = (const float*)d_in[0];
  const float* Wih0 = (const float*)d_in[1];
  const float* Whh0 = (const float*)d_in[2];
  const float* bih0 = (const float*)d_in[3];
  const float* bhh0 = (const float*)d_in[4];
  const float* Wih1 = (const float*)d_in[5];
  const float* Whh1 = (const float*)d_in[6];
  const float* bih1 = (const float*)d_in[7];
  const float* bhh1 = (const float*)d_in[8];
  const float* Wih2 = (const float*)d_in[9];
  const float* Whh2 = (const float*)d_in[10];
  const float* bih2 = (const float*)d_in[11];
  const float* bhh2 = (const float*)d_in[12];
  const float* fc1w = (const float*)d_in[13];
  const float* fc1b = (const float*)d_in[14];
  const float* fc2w = (const float*)d_in[15];
  const float* fc2b = (const float*)d_in[16];

  rnn_ck<<<dim3(4096 / BPB), dim3(192), 0, stream>>>(
      x, Wih0, Whh0, bih0, bhh0, Wih1, Whh1, bih1, bhh1,
      Wih2, Whh2, bih2, bhh2, fc1w, fc1b, fc2w, fc2b, (float*)d_out);
}

// Round 3
// 167.483 us; speedup vs baseline: 1.1529x; 1.0729x over previous
//
#include <hip/hip_runtime.h>

typedef short  s16x8 __attribute__((ext_vector_type(8)));   // 8 bf16 bit patterns
typedef float  f32x4 __attribute__((ext_vector_type(4)));
typedef float  f32x2 __attribute__((ext_vector_type(2)));
typedef unsigned int u32;
typedef unsigned int u32x4 __attribute__((ext_vector_type(4)));
typedef unsigned short u16;

#define DEVI static __device__ __forceinline__

#if __has_builtin(__builtin_amdgcn_exp2f)
#define EXP2(v) __builtin_amdgcn_exp2f(v)   // raw v_exp_f32 (R11-proven)
#else
#define EXP2(v) exp2f(v)
#endif

constexpr int T_  = 128;
constexpr int F_  = 14;
constexpr int H_  = 64;
constexpr int BPB = 16;   // batch rows per block
constexpr int K_  = 8;    // timesteps per epoch (chunk)
constexpr int NCH = T_ / K_;   // 16 chunks

constexpr int HF_BYTES   = 2 * 2 * K_ * 2 * 64 * 16;   // 65536
constexpr int XBUF_BYTES = 2 * K_ * 64 * 16;           // 16384
constexpr int SMEM_BYTES = HF_BYTES + XBUF_BYTES;      // 81920 (dynamic, opt-in)

DEVI u16 f2bf(float f) {                     // RNE, one-time weight convert
  u32 u = __builtin_bit_cast(u32, f);
  u += 0x7fffu + ((u >> 16) & 1u);
  return (u16)(u >> 16);
}
// HW packed bf16 convert (RNE): 1 instr replaces 5-op manual pack.
DEVI u32 cvtpk(float a, float b) {           // lo16 = bf16(a), hi16 = bf16(b)
  u32 r;
  asm("v_cvt_pk_bf16_f32 %0, %1, %2" : "=v"(r) : "v"(a), "v"(b));
  return r;
}
// B-frag kt from tanh'd acc tiles: elements 0-3 = tile kt, 4-7 = tile kt+2
DEVI s16x8 packfrag(const f32x4& a, const f32x4& b) {
  u32x4 p;
  p[0] = cvtpk(a[0], a[1]); p[1] = cvtpk(a[2], a[3]);
  p[2] = cvtpk(b[0], b[1]); p[3] = cvtpk(b[2], b[3]);
  return __builtin_bit_cast(s16x8, p);
}
// tanh; mul/add/fma as packed fp32 (bit-identical to scalar), trans scalar.
DEVI f32x4 tanh4(const f32x4& v) {
  const f32x4 kC = -2.8853900817779268f;
  f32x4 t = v * kC;                          // 2x v_pk_mul_f32
  f32x4 e;
  e[0] = EXP2(t[0]); e[1] = EXP2(t[1]);
  e[2] = EXP2(t[2]); e[3] = EXP2(t[3]);
  const f32x4 kOne = 1.0f;
  f32x4 d = e + kOne;                        // 2x v_pk_add_f32
  f32x4 r;
  r[0] = __builtin_amdgcn_rcpf(d[0]); r[1] = __builtin_amdgcn_rcpf(d[1]);
  r[2] = __builtin_amdgcn_rcpf(d[2]); r[3] = __builtin_amdgcn_rcpf(d[3]);
  const f32x4 kTwo = 2.0f, kNegOne = -1.0f;
  return __builtin_elementwise_fma(kTwo, r, kNegOne);   // 2x v_pk_fma_f32
}
DEVI f32x4 MFMA(s16x8 a, s16x8 b, f32x4 c) {
  return __builtin_amdgcn_mfma_f32_16x16x32_bf16(a, b, c, 0, 0, 0);
}
DEVI s16x8 ldrow8(const float* p) {          // 8 contiguous fp32 -> bf16 A-frag
  const f32x4 a = ((const f32x4*)p)[0];
  const f32x4 b = ((const f32x4*)p)[1];
  s16x8 r;
  r[0] = (short)f2bf(a[0]); r[1] = (short)f2bf(a[1]);
  r[2] = (short)f2bf(a[2]); r[3] = (short)f2bf(a[3]);
  r[4] = (short)f2bf(b[0]); r[5] = (short)f2bf(b[1]);
  r[6] = (short)f2bf(b[2]); r[7] = (short)f2bf(b[3]);
  return r;
}

// 4 waves/block now.  Waves 0-2: layer w recurrence (R8 math/layout, R1 LDS
// prefetch + 1-deep q pipeline, R2 cvt_pk/packed-fp32).  THIS ROUND:
//  * wave 3 = x producer on the previously-idle 4th SIMD: does the global
//    loads + bf16 convert + frag staging for wave0 via a 16KiB double-buffered
//    LDS region (same chunk-parity protocol as hf).  Wave0's per-step cost
//    drops by ~15 instrs (it was the longest wave).
//  * q pipeline seeds bc into its first MFMA accumulator; p-MFMAs accumulate
//    serially INTO qc -> the 8 v_pk_add (p+q) per step are gone and one add
//    leaves the dependence chain.  (fp32 summation reorder only.)
//  * p-MFMAs issue at step top (critical chain), qn after, tanh last.
// LDS = 80KiB dynamic (opt-in attribute; precedent: 128KiB kernels on gfx950).
__global__ __launch_bounds__(256, 1) void rnn_ck(
    const float* __restrict__ x,
    const float* __restrict__ Wih0, const float* __restrict__ Whh0,
    const float* __restrict__ bih0, const float* __restrict__ bhh0,
    const float* __restrict__ Wih1, const float* __restrict__ Whh1,
    const float* __restrict__ bih1, const float* __restrict__ bhh1,
    const float* __restrict__ Wih2, const float* __restrict__ Whh2,
    const float* __restrict__ bih2, const float* __restrict__ bhh2,
    const float* __restrict__ fc1w, const float* __restrict__ fc1b,
    const float* __restrict__ fc2w, const float* __restrict__ fc2b,
    float* __restrict__ out)
{
  extern __shared__ __align__(16) char smem[];
  // hf[par][layer01][k][frag][lane], xbuf[par][k][lane]
  u32x4 (*hf)[2][K_][2][64] = (u32x4 (*)[2][K_][2][64])smem;
  u32x4 (*xbuf)[K_][64]     = (u32x4 (*)[K_][64])(smem + HF_BYTES);

  const int tid  = threadIdx.x;
  const int w    = tid >> 6;        // waves 0-2: layer id; wave 3: x producer
  const int lane = tid & 63;
  const int g    = lane >> 4;
  const int m    = lane & 15;
  const int b0   = blockIdx.x * BPB;

  f32x4 z4; z4[0] = 0.f; z4[1] = 0.f; z4[2] = 0.f; z4[3] = 0.f;

  // ---- per-wave (per-layer) weights, register-resident (waves 0-2 only) ----
  s16x8 Ax[4], Ai[4][2], Ah[4][2];
  f32x4 bc[4];
  if (w < 3) {
    const float* Wi = Wih1; const float* Wh = Whh0;
    const float* bi = bih0; const float* bh = bhh0;
    if (w == 1)      { Wi = Wih1; Wh = Whh1; bi = bih1; bh = bhh1; }
    else if (w == 2) { Wi = Wih2; Wh = Whh2; bi = bih2; bh = bhh2; }
    #pragma unroll
    for (int n = 0; n < 4; n++) {
      const int Lr = 32 * (n & 1) + 8 * (m >> 2) + 4 * (n >> 1) + (m & 3);
      if (w == 0) {                      // input side 64x14, zero-pad K to 32
        s16x8 r;
        #pragma unroll
        for (int j2 = 0; j2 < 8; j2++) {
          const int kk = 8 * g + j2;
          r[j2] = (kk < F_) ? (short)f2bf(Wih0[Lr * F_ + kk]) : (short)0;
        }
        Ax[n] = r;
        Ai[n][0] = r; Ai[n][1] = r;      // dead in wave0
      } else {
        #pragma unroll
        for (int kt = 0; kt < 2; kt++)
          Ai[n][kt] = ldrow8(Wi + Lr * H_ + 32 * kt + 8 * g);
        Ax[n] = Ai[n][0];                // dead in waves 1/2
      }
      #pragma unroll
      for (int kt = 0; kt < 2; kt++)
        Ah[n][kt] = ldrow8(Wh + Lr * H_ + 32 * kt + 8 * g);
      const int Lb = 32 * (n & 1) + 8 * g + 4 * (n >> 1);
      bc[n] = *(const f32x4*)(bi + Lb) + *(const f32x4*)(bh + Lb);
    }
  }

  // ---- hh-state frags (own layer), zero init (h(-1)=0 in REGISTERS) ----
  s16x8 F[2];
  {
    s16x8 z;
    #pragma unroll
    for (int i = 0; i < 8; i++) z[i] = 0;
    F[0] = z; F[1] = z;
  }
  f32x4 h2v[4];
  #pragma unroll
  for (int n = 0; n < 4; n++) h2v[n] = z4;

  // ---- x producer helpers (wave 3 only in steady state) ----
  const float* xrow = x + (size_t)(b0 + m) * T_ * F_;
  auto ldraw = [&](int t, f32x4& ra, f32x4& rb) {    // R8-proven float2 loads
    const float* p = xrow + t * F_;
    if (g == 0) {
      f32x2 p0 = *(const f32x2*)(p),     p1 = *(const f32x2*)(p + 2);
      f32x2 p2 = *(const f32x2*)(p + 4), p3 = *(const f32x2*)(p + 6);
      ra[0] = p0[0]; ra[1] = p0[1]; ra[2] = p1[0]; ra[3] = p1[1];
      rb[0] = p2[0]; rb[1] = p2[1]; rb[2] = p3[0]; rb[3] = p3[1];
    } else if (g == 1) {
      f32x2 p4 = *(const f32x2*)(p + 8), p5 = *(const f32x2*)(p + 10);
      f32x2 p6 = *(const f32x2*)(p + 12);
      ra[0] = p4[0]; ra[1] = p4[1]; ra[2] = p5[0]; ra[3] = p5[1];
      rb[0] = p6[0]; rb[1] = p6[1]; rb[2] = 0.f;   rb[3] = 0.f;
    } else {
      ra = z4; rb = z4;
    }
  };
  auto cvtraw = [&](const f32x4& ra, const f32x4& rb) -> s16x8 {
    u32x4 p;
    p[0] = cvtpk(ra[0], ra[1]); p[1] = cvtpk(ra[2], ra[3]);
    p[2] = cvtpk(rb[0], rb[1]); p[3] = cvtpk(rb[2], rb[3]);
    return __builtin_bit_cast(s16x8, p);
  };

  // ---- prologue: wave3 stages chunk 0 into xbuf[0] ----
  if (w == 3) {
    f32x4 ra[K_], rb[K_];
    #pragma unroll
    for (int k = 0; k < K_; k++) ldraw(k, ra[k], rb[k]);
    #pragma unroll
    for (int k = 0; k < K_; k++)
      xbuf[0][k][lane] = __builtin_bit_cast(u32x4, cvtraw(ra[k], rb[k]));
  }
  __syncthreads();

  // ---- chunked pipelined loop: epoch e, wave w does chunk c = e - w ----
  #pragma unroll 1
  for (int e = 0; e < NCH + 2; e++) {
    const int wb = e & 1, rbuf = wb ^ 1;

    if (w == 3) {
      // produce chunk e+1 into xbuf[(e+1)&1] == xbuf[rbuf]
      if (e < NCH - 1) {
        f32x4 ra[K_], rb[K_];
        #pragma unroll
        for (int k = 0; k < K_; k++) ldraw((e + 1) * K_ + k, ra[k], rb[k]);
        #pragma unroll
        for (int k = 0; k < K_; k++)
          xbuf[rbuf][k][lane] = __builtin_bit_cast(u32x4, cvtraw(ra[k], rb[k]));
      }
    } else {
      const int c = e - w;
      if (c >= 0 && c < NCH) {           // wave-uniform
        // ---- chunk-top input fetch into registers ----
        s16x8 cur[K_];                   // wave0: x frags (chunk c, parity wb)
        f32x4 stage[2 * K_];             // waves1/2: prev-layer h frags
        if (w == 0) {
          #pragma unroll
          for (int k = 0; k < K_; k++)
            cur[k] = __builtin_bit_cast(s16x8, xbuf[wb][k][lane]);
        } else {
          const int src = w - 1;
          #pragma unroll
          for (int k = 0; k < K_; k++) {
            stage[k]      = __builtin_bit_cast(f32x4, hf[rbuf][src][k][0][lane]);
            stage[K_ + k] = __builtin_bit_cast(f32x4, hf[rbuf][src][k][1][lane]);
          }
        }

        // ---- q prologue, seeded with bc (bias folded into q accumulator) ----
        f32x4 qc[4], qn[4];
        if (w == 0) {
          #pragma unroll
          for (int n = 0; n < 4; n++) qc[n] = MFMA(Ax[n], cur[0], bc[n]);
        } else {
          const s16x8 P0 = __builtin_bit_cast(s16x8, stage[0]);
          const s16x8 P1 = __builtin_bit_cast(s16x8, stage[K_]);
          #pragma unroll
          for (int n = 0; n < 4; n++) qc[n] = MFMA(Ai[n][0], P0, bc[n]);
          #pragma unroll
          for (int n = 0; n < 4; n++) qc[n] = MFMA(Ai[n][1], P1, qc[n]);
        }

        #pragma unroll
        for (int k = 0; k < K_; k++) {
          // chain first: p accumulates INTO qc (bc+q already there).
          // Tiles 0,2 first so F[0]'s inputs retire first.
          f32x4 p[4];
          p[0] = MFMA(Ah[0][0], F[0], qc[0]);
          p[2] = MFMA(Ah[2][0], F[0], qc[2]);
          p[1] = MFMA(Ah[1][0], F[0], qc[1]);
          p[3] = MFMA(Ah[3][0], F[0], qc[3]);
          p[0] = MFMA(Ah[0][1], F[1], p[0]);
          p[2] = MFMA(Ah[2][1], F[1], p[2]);
          p[1] = MFMA(Ah[1][1], F[1], p[1]);
          p[3] = MFMA(Ah[3][1], F[1], p[3]);

          // next step's q — independent, fills MFMA pipe during tanh
          if (k + 1 < K_) {
            if (w == 0) {
              #pragma unroll
              for (int n = 0; n < 4; n++) qn[n] = MFMA(Ax[n], cur[k + 1], bc[n]);
            } else {
              const s16x8 P0 = __builtin_bit_cast(s16x8, stage[k + 1]);
              const s16x8 P1 = __builtin_bit_cast(s16x8, stage[K_ + k + 1]);
              #pragma unroll
              for (int n = 0; n < 4; n++) qn[n] = MFMA(Ai[n][0], P0, bc[n]);
              #pragma unroll
              for (int n = 0; n < 4; n++) qn[n] = MFMA(Ai[n][1], P1, qn[n]);
            }
          }

          // F[0] first (tiles 0,2) so next step's first MFMA pair starts early
          f32x4 hv0 = tanh4(p[0]);
          f32x4 hv2 = tanh4(p[2]);
          F[0] = packfrag(hv0, hv2);
          f32x4 hv1 = tanh4(p[1]);
          f32x4 hv3 = tanh4(p[3]);
          F[1] = packfrag(hv1, hv3);

          if (w < 2) {
            hf[wb][w][k][0][lane] = __builtin_bit_cast(u32x4, F[0]);
            hf[wb][w][k][1][lane] = __builtin_bit_cast(u32x4, F[1]);
          } else if (c == NCH - 1 && k == K_ - 1) {
            h2v[0] = hv0; h2v[1] = hv1;    // fp32 h2 for head
            h2v[2] = hv2; h2v[3] = hv3;
          }

          if (k + 1 < K_) {
            #pragma unroll
            for (int n = 0; n < 4; n++) qc[n] = qn[n];
          }
        }
      }
    }
    __syncthreads();   // single chunk-granular barrier (R8 dbuf protocol)
  }

  // ---- FC head: h2l overlays dead hf; wave 2 un-permutes, wave 0 computes ----
  float (*h2l)[68] = (float (*)[68])smem;
  if (w == 2) {
    #pragma unroll
    for (int n = 0; n < 4; n++) {
      const int Lb = 32 * (n & 1) + 8 * g + 4 * (n >> 1);
      *(f32x4*)&h2l[m][Lb] = h2v[n];
    }
  }
  __syncthreads();

  if (w == 0) {
    float hr[64];
    #pragma unroll
    for (int q = 0; q < 16; q++) {
      f32x4 v = *(const f32x4*)&h2l[m][4 * q];
      hr[4 * q + 0] = v[0]; hr[4 * q + 1] = v[1];
      hr[4 * q + 2] = v[2]; hr[4 * q + 3] = v[3];
    }
    float acc2 = 0.f;
    #pragma unroll
    for (int jj = 0; jj < 8; jj++) {
      const int jf = 8 * g + jj;
      float s = fc1b[jf];
      const f32x4* wp = (const f32x4*)(fc1w + jf * H_);
      #pragma unroll
      for (int kq = 0; kq < 16; kq++) {
        f32x4 wv = wp[kq];
        s += hr[4 * kq + 0] * wv[0] + hr[4 * kq + 1] * wv[1]
           + hr[4 * kq + 2] * wv[2] + hr[4 * kq + 3] * wv[3];
      }
      s = fmaxf(s, 0.f);
      acc2 += s * fc2w[jf];
    }
    acc2 += __shfl_xor(acc2, 16, 64);
    acc2 += __shfl_xor(acc2, 32, 64);
    if (lane < 16) out[b0 + m] = acc2 + fc2b[0];
  }
}

extern "C" void kernel_launch(void* const* d_in, const int* in_sizes, int n_in,
                              void* d_out, int out_size, void* d_ws, size_t ws_size,
                              hipStream_t stream) {
  const float* x    = (const float*)d_in[0];
  const float* Wih0 = (const float*)d_in[1];
  const float* Whh0 = (const float*)d_in[2];
  const float* bih0 = (const float*)d_in[3];
  const float* bhh0 = (const float*)d_in[4];
  const float* Wih1 = (const float*)d_in[5];
  const float* Whh1 = (const float*)d_in[6];
  const float* bih1 = (const float*)d_in[7];
  const float* bhh1 = (const float*)d_in[8];
  const float* Wih2 = (const float*)d_in[9];
  const float* Whh2 = (const float*)d_in[10];
  const float* bih2 = (const float*)d_in[11];
  const float* bhh2 = (const float*)d_in[12];
  const float* fc1w = (const float*)d_in[13];
  const float* fc1b = (const float*)d_in[14];
  const float* fc2w = (const float*)d_in[15];
  const float* fc2b = (const float*)d_in[16];

  static bool s_attr_set = false;
  if (!s_attr_set) {
    (void)hipFuncSetAttribute((const void*)rnn_ck,
                              hipFuncAttributeMaxDynamicSharedMemorySize,
                              SMEM_BYTES);
    s_attr_set = true;
  }

  rnn_ck<<<dim3(4096 / BPB), dim3(256), SMEM_BYTES, stream>>>(
      x, Wih0, Whh0, bih0, bhh0, Wih1, Whh1, bih1, bhh1,
      Wih2, Whh2, bih2, bhh2, fc1w, fc1b, fc2w, fc2b, (float*)d_out);
}